// Round 10
// baseline (601.708 us; speedup 1.0000x reference)
//
#include <hip/hip_runtime.h>

#define NN 100000
#define EE 1000000
#define FF 128
#define HH 64
#define GG 128
#define NB 391    // scan blocks per half: 391*256 >= NN
#define MMB 1563  // matmul blocks: ceil(NN/64)
#define NQ 4      // dst quarters
#define QN 25000  // nodes per quarter
#define QCAP 260000 // msg rows capacity per quarter (E/4 + slack)

__device__ inline unsigned short f2bf(float f) {
    unsigned u = __float_as_uint(f);
    u += 0x7fffu + ((u >> 16) & 1u);
    return (unsigned short)(u >> 16);
}
__device__ inline float bf2f(unsigned short h) {
    return __uint_as_float((unsigned)h << 16);
}

// ---------- CSR build: dst-CSR (row_ptr/cursor) + src-CSC positions ----------
__global__ void k_hist2(const int* __restrict__ ei, int* __restrict__ cnt,
                        int* __restrict__ cnt2) {
    int e = blockIdx.x * 256 + threadIdx.x;
    if (e < EE) {
        atomicAdd(&cnt[ei[EE + e]], 1);   // in-degree (dst)
        atomicAdd(&cnt2[ei[e]], 1);       // out-degree (src)
    }
}

__global__ void k_scan1(const int* __restrict__ cnt, const int* __restrict__ cnt2,
                        int* __restrict__ part, float* __restrict__ dis) {
    const int half = (blockIdx.x >= NB) ? 1 : 0;
    const int bid  = blockIdx.x - half * NB;
    const int i = bid * 256 + threadIdx.x;
    const int* c = half ? cnt2 : cnt;
    int v = (i < NN) ? c[i] : 0;
    if (!half && i < NN) dis[i] = rsqrtf((float)(v + 1));
    for (int o = 1; o < 64; o <<= 1) v += __shfl_xor(v, o);
    __shared__ int ws[4];
    if ((threadIdx.x & 63) == 0) ws[threadIdx.x >> 6] = v;
    __syncthreads();
    if (threadIdx.x == 0) part[blockIdx.x] = ws[0] + ws[1] + ws[2] + ws[3];
}

__global__ void k_scan2(int* __restrict__ part) {   // two independent excl scans
    __shared__ int buf[1024];
    const int t = threadIdx.x;
    const int h = t >> 9;          // half 0/1
    const int j = t & 511;
    int v = (j < NB) ? part[h * NB + j] : 0;
    buf[t] = v; __syncthreads();
    for (int o = 1; o < 512; o <<= 1) {
        int u = (j >= o) ? buf[t - o] : 0;
        __syncthreads();
        buf[t] += u;
        __syncthreads();
    }
    if (j < NB) part[h * NB + j] = buf[t] - v;
}

__global__ void k_scan3(const int* __restrict__ cnt, const int* __restrict__ cnt2,
                        const int* __restrict__ part,
                        int* __restrict__ row_ptr, int* __restrict__ row_ptr2,
                        int* __restrict__ cursor, int* __restrict__ cursor2) {
    const int half = (blockIdx.x >= NB) ? 1 : 0;
    const int bid  = blockIdx.x - half * NB;
    const int i = bid * 256 + threadIdx.x;
    const int* c  = half ? cnt2 : cnt;
    int* rp  = half ? row_ptr2 : row_ptr;
    int* cur = half ? cursor2 : cursor;
    int v = (i < NN) ? c[i] : 0;
    const int lane = threadIdx.x & 63, w = threadIdx.x >> 6;
    int incl = v;
    for (int o = 1; o < 64; o <<= 1) { int u = __shfl_up(incl, o); if (lane >= o) incl += u; }
    __shared__ int ws[4];
    if (lane == 63) ws[w] = incl;
    __syncthreads();
    int woff = 0;
    for (int k = 0; k < w; ++k) woff += ws[k];
    const int excl = incl - v + woff + part[blockIdx.x];
    if (i < NN) { rp[i] = excl; cur[i] = excl; }
    if (i == 0) rp[NN] = EE;
}

// ---------- matmul body: int8 row-quantized output (scale S[r]) ----------
template<int K, int XBF>
__device__ __forceinline__ void
mm_body(const void* __restrict__ Xv, const float* __restrict__ W,
        const float* __restrict__ dis, unsigned* __restrict__ Y8,
        float* __restrict__ S, float* __restrict__ Wl, int bid) {
    for (int i = threadIdx.x; i < K * HH; i += 256) Wl[i] = W[i];
    __syncthreads();
    const int lane = threadIdx.x & 63;
    const int wv   = threadIdx.x >> 6;
    const int c4   = (lane & 15) * 4;
    const int rsg  = lane >> 4;
    const int r0   = bid * 64 + wv * 16 + rsg * 4;

    const char* Xb = (const char*)Xv;
    const size_t rb = (size_t)K * (XBF ? 2 : 4);
    const char* xr0; const char* xr1; const char* xr2; const char* xr3;
    {
        int a = r0, b_ = r0 + 1, c = r0 + 2, d = r0 + 3;
        if (a > NN - 1) a = NN - 1;
        if (b_ > NN - 1) b_ = NN - 1;
        if (c > NN - 1) c = NN - 1;
        if (d > NN - 1) d = NN - 1;
        xr0 = Xb + (size_t)a * rb; xr1 = Xb + (size_t)b_ * rb;
        xr2 = Xb + (size_t)c * rb; xr3 = Xb + (size_t)d * rb;
    }
    float4 acc0 = {0,0,0,0}, acc1 = {0,0,0,0}, acc2 = {0,0,0,0}, acc3 = {0,0,0,0};

#pragma unroll 8
    for (int k4 = 0; k4 < K / 4; ++k4) {
        float4 x0, x1, x2, x3;
        if (XBF) {
            ushort4 u0 = *(const ushort4*)(xr0 + k4 * 8);
            ushort4 u1 = *(const ushort4*)(xr1 + k4 * 8);
            ushort4 u2 = *(const ushort4*)(xr2 + k4 * 8);
            ushort4 u3 = *(const ushort4*)(xr3 + k4 * 8);
            x0 = {bf2f(u0.x), bf2f(u0.y), bf2f(u0.z), bf2f(u0.w)};
            x1 = {bf2f(u1.x), bf2f(u1.y), bf2f(u1.z), bf2f(u1.w)};
            x2 = {bf2f(u2.x), bf2f(u2.y), bf2f(u2.z), bf2f(u2.w)};
            x3 = {bf2f(u3.x), bf2f(u3.y), bf2f(u3.z), bf2f(u3.w)};
        } else {
            x0 = *(const float4*)(xr0 + k4 * 16);
            x1 = *(const float4*)(xr1 + k4 * 16);
            x2 = *(const float4*)(xr2 + k4 * 16);
            x3 = *(const float4*)(xr3 + k4 * 16);
        }
        const float4 w0 = *(const float4*)&Wl[(k4 * 4 + 0) * HH + c4];
        const float4 w1 = *(const float4*)&Wl[(k4 * 4 + 1) * HH + c4];
        const float4 w2 = *(const float4*)&Wl[(k4 * 4 + 2) * HH + c4];
        const float4 w3 = *(const float4*)&Wl[(k4 * 4 + 3) * HH + c4];
#define FMA4(A, XS) \
        A.x = fmaf(XS.x, w0.x, A.x); A.y = fmaf(XS.x, w0.y, A.y); \
        A.z = fmaf(XS.x, w0.z, A.z); A.w = fmaf(XS.x, w0.w, A.w); \
        A.x = fmaf(XS.y, w1.x, A.x); A.y = fmaf(XS.y, w1.y, A.y); \
        A.z = fmaf(XS.y, w1.z, A.z); A.w = fmaf(XS.y, w1.w, A.w); \
        A.x = fmaf(XS.z, w2.x, A.x); A.y = fmaf(XS.z, w2.y, A.y); \
        A.z = fmaf(XS.z, w2.z, A.z); A.w = fmaf(XS.z, w2.w, A.w); \
        A.x = fmaf(XS.w, w3.x, A.x); A.y = fmaf(XS.w, w3.y, A.y); \
        A.z = fmaf(XS.w, w3.z, A.z); A.w = fmaf(XS.w, w3.w, A.w);
        FMA4(acc0, x0) FMA4(acc1, x1) FMA4(acc2, x2) FMA4(acc3, x3)
#undef FMA4
    }
#define STORE(I, A) { \
        const int r = r0 + I; \
        if (r < NN) { \
            const float d = dis[r]; \
            const float ax = A.x * d, ay = A.y * d, az = A.z * d, aw = A.w * d; \
            float m = fmaxf(fmaxf(fabsf(ax), fabsf(ay)), fmaxf(fabsf(az), fabsf(aw))); \
            m = fmaxf(m, __shfl_xor(m, 1)); m = fmaxf(m, __shfl_xor(m, 2)); \
            m = fmaxf(m, __shfl_xor(m, 4)); m = fmaxf(m, __shfl_xor(m, 8)); \
            const float inv = 127.0f / m; \
            int q0 = __float2int_rn(ax * inv), q1 = __float2int_rn(ay * inv); \
            int q2 = __float2int_rn(az * inv), q3 = __float2int_rn(aw * inv); \
            if (m == 0.0f) { q0 = q1 = q2 = q3 = 0; } \
            const unsigned pk = (q0 & 0xff) | ((q1 & 0xff) << 8) | \
                                ((q2 & 0xff) << 16) | ((q3 & 0xff) << 24); \
            Y8[(size_t)r * 16 + (c4 >> 2)] = pk; \
            if (c4 == 0) S[r] = m * (1.0f / 127.0f); \
        } }
    STORE(0, acc0) STORE(1, acc1) STORE(2, acc2) STORE(3, acc3)
#undef STORE
}

template<int K, int XBF>
__global__ __launch_bounds__(256) void
k_matmul_b(const void* __restrict__ X, const float* __restrict__ W,
           const float* __restrict__ dis, unsigned* __restrict__ Y8,
           float* __restrict__ S) {
    __shared__ float Wl[K * HH];
    mm_body<K, XBF>(X, W, dis, Y8, S, Wl, blockIdx.x);
}

// fused: blocks [0,MMB) run matmul-1; rest do the double-place (dst slot p; csc_pos by src)
__global__ __launch_bounds__(256) void
k_mm1_place(const float* __restrict__ X, const float* __restrict__ W,
            const float* __restrict__ dis, unsigned* __restrict__ Y8,
            float* __restrict__ S, const int* __restrict__ ei,
            int* __restrict__ cursor, int* __restrict__ cursor2,
            int* __restrict__ csc_pos) {
    __shared__ float Wl[FF * HH];
    if (blockIdx.x < MMB) {
        mm_body<FF, 0>(X, W, dis, Y8, S, Wl, blockIdx.x);
    } else {
        int e = (blockIdx.x - MMB) * 256 + threadIdx.x;
        if (e < EE) {
            const int s = ei[e], d = ei[EE + e];
            const int p = atomicAdd(&cursor[d], 1);
            const int q = atomicAdd(&cursor2[s], 1);
            csc_pos[q] = p;
        }
    }
}

// ---------- phase A: src-major scatter-store of messages ----------
// 16-lane team per src: row read once (sequential), stored to each out-edge's
// dst-CSR slot within this quarter. 64B contiguous stores, no load chains.
__global__ __launch_bounds__(256) void
k_scatA(const int* __restrict__ row_ptr2, const int* __restrict__ csc_pos,
        const unsigned* __restrict__ H8, const float* __restrict__ S,
        const int* __restrict__ row_ptr, int n0, int n1,
        unsigned* __restrict__ msg, float* __restrict__ msgS) {
    const int node = blockIdx.x * 16 + (threadIdx.x >> 4);
    const int li   = threadIdx.x & 15;
    const int tbase = (threadIdx.x & 63) & ~15;    // wave-relative team base
    const unsigned rv = H8[(size_t)node * 16 + li];
    const float sv = S[node];
    const int q0 = row_ptr2[node], q1 = row_ptr2[node + 1];
    const int PB0 = row_ptr[n0], PB1 = row_ptr[n1];
    for (int base = q0; base < q1; base += 16) {
        const int myp = (base + li < q1) ? csc_pos[base + li] : -1;
        const int cnt = min(16, q1 - base);
        for (int j = 0; j < cnt; ++j) {
            const int p = __shfl(myp, tbase + j);
            if (p >= PB0 && p < PB1) {
                msg[(size_t)(p - PB0) * 16 + li] = rv;
                if (li == 0) msgS[p - PB0] = sv;
            }
        }
    }
}

// ---------- phase B: dst-major streaming segment-sum ----------
template<bool POOL>
__global__ __launch_bounds__(256) void
k_gconvB(const int* __restrict__ row_ptr, const float* __restrict__ dis,
         const unsigned* __restrict__ H8, const float* __restrict__ S,
         const unsigned* __restrict__ msg, const float* __restrict__ msgS,
         const float* __restrict__ b, int n0,
         unsigned short* __restrict__ A, const int* __restrict__ batch,
         float* __restrict__ g) {
    const int node = n0 + blockIdx.x * 4 + (threadIdx.x >> 6);
    const int lane = threadIdx.x & 63;
    const int li = lane & 15, qr = lane >> 4;
    const int PB0 = row_ptr[n0];
    const int p0  = row_ptr[node] - PB0;
    const int deg = row_ptr[node + 1] - PB0 - p0;
    float ac0 = 0.f, ac1 = 0.f, ac2 = 0.f, ac3 = 0.f;
    if (qr == 0) {   // self contribution
        const unsigned v = H8[(size_t)node * 16 + li];
        const float s = S[node];
        ac0 = s * (float)(signed char)(v);
        ac1 = s * (float)(signed char)(v >> 8);
        ac2 = s * (float)(signed char)(v >> 16);
        ac3 = s * (float)(signed char)(v >> 24);
    }
#pragma unroll 2
    for (int i = qr; i < deg; i += 4) {   // contiguous 256B per wave-iter
        const unsigned v = msg[(size_t)(p0 + i) * 16 + li];
        const float s = msgS[p0 + i];
        ac0 = fmaf(s, (float)(signed char)(v), ac0);
        ac1 = fmaf(s, (float)(signed char)(v >> 8), ac1);
        ac2 = fmaf(s, (float)(signed char)(v >> 16), ac2);
        ac3 = fmaf(s, (float)(signed char)(v >> 24), ac3);
    }
    ac0 += __shfl_xor(ac0, 16); ac0 += __shfl_xor(ac0, 32);
    ac1 += __shfl_xor(ac1, 16); ac1 += __shfl_xor(ac1, 32);
    ac2 += __shfl_xor(ac2, 16); ac2 += __shfl_xor(ac2, 32);
    ac3 += __shfl_xor(ac3, 16); ac3 += __shfl_xor(ac3, 32);
    const float c0 = __shfl(ac0, lane >> 2);
    const float c1 = __shfl(ac1, lane >> 2);
    const float c2 = __shfl(ac2, lane >> 2);
    const float c3 = __shfl(ac3, lane >> 2);
    const int m = lane & 3;
    const float acc = (m == 0) ? c0 : (m == 1) ? c1 : (m == 2) ? c2 : c3;

    const float dd = dis[node];
    float v = acc * dd + b[lane];
    v = fmaxf(v, 0.0f);
    if (POOL) {
        unsafeAtomicAdd(&g[(size_t)batch[node] * HH + lane], v);
    } else {
        A[(size_t)node * HH + lane] = f2bf(v);
    }
}

// ---------- head ----------
__global__ void k_head1(const float* __restrict__ g, const float* __restrict__ W,
                        const float* __restrict__ b, float* __restrict__ g2) {
    const int idx = blockIdx.x * 256 + threadIdx.x;
    const int row = idx >> 6;
    const int col = idx & 63;
    const float* gr = g + (size_t)row * HH;
    float acc = b[col];
#pragma unroll
    for (int k = 0; k < HH; ++k) acc = fmaf(gr[k], W[k * HH + col], acc);
    g2[idx] = acc > 0.0f ? acc : 0.0f;
}

__global__ void k_head2(const float* __restrict__ g2, const float* __restrict__ W,
                        const float* __restrict__ b, float* __restrict__ out) {
    const int r = threadIdx.x;
    if (r >= GG) return;
    const float* gr = g2 + (size_t)r * HH;
    float acc = 0.0f;
#pragma unroll
    for (int k = 0; k < HH; ++k) acc = fmaf(gr[k], W[k], acc);
    out[r] = acc + b[0];
}

extern "C" void kernel_launch(void* const* d_in, const int* in_sizes, int n_in,
                              void* d_out, int out_size, void* d_ws, size_t ws_size,
                              hipStream_t stream) {
    const float* x   = (const float*)d_in[0];
    const int*   ei  = (const int*)d_in[1];
    const int*   bat = (const int*)d_in[2];
    const float* W1  = (const float*)d_in[3];
    const float* b1  = (const float*)d_in[4];
    const float* W2  = (const float*)d_in[5];
    const float* b2  = (const float*)d_in[6];
    const float* Wl1 = (const float*)d_in[7];
    const float* bl1 = (const float*)d_in[8];
    const float* Wl2 = (const float*)d_in[9];
    const float* bl2 = (const float*)d_in[10];
    float* out = (float*)d_out;

    char* w = (char*)d_ws;
    float*    dis      = (float*)(w);                  // 400,128
    int*      cnt      = (int*)  (w + 400128);         // 400,128
    int*      cnt2     = (int*)  (w + 800256);         // 400,128
    int*      row_ptr  = (int*)  (w + 1200384);        // 400,384
    int*      row_ptr2 = (int*)  (w + 1600768);        // 400,384
    int*      cursor   = (int*)  (w + 2001152);        // 400,128
    int*      cursor2  = (int*)  (w + 2401280);        // 400,128
    int*      part     = (int*)  (w + 2801408);        // 8,192
    int*      csc_pos  = (int*)  (w + 2809600);        // 4,000,000
    float*    S        = (float*)(w + 6809600);        // 400,128
    unsigned* H8       = (unsigned*)(w + 7209728);     // 6,400,000
    float*    msgS     = (float*)(w + 13609728);       // 1,040,000
    unsigned* msg      = (unsigned*)(w + 14649728);    // 16,640,000
    unsigned short* A  = (unsigned short*)(w + 31289728); // 12,800,000 (bf16)
    float*    g        = (float*)(w + 44089728);       // pool + head scratch
    float*    g2       = g + GG * HH;

    // ---- CSR/CSC build ----
    hipMemsetAsync(cnt, 0, 800256, stream);            // cnt + cnt2
    k_hist2<<<(EE + 255) / 256, 256, 0, stream>>>(ei, cnt, cnt2);
    k_scan1<<<2 * NB, 256, 0, stream>>>(cnt, cnt2, part, dis);
    k_scan2<<<1, 1024, 0, stream>>>(part);
    k_scan3<<<2 * NB, 256, 0, stream>>>(cnt, cnt2, part, row_ptr, row_ptr2, cursor, cursor2);

    // ---- conv1 matmul fused with edge placement ----
    k_mm1_place<<<MMB + (EE + 255) / 256, 256, 0, stream>>>(
        x, W1, dis, H8, S, ei, cursor, cursor2, csc_pos);
    for (int k = 0; k < NQ; ++k) {
        k_scatA<<<NN / 16, 256, 0, stream>>>(row_ptr2, csc_pos, H8, S, row_ptr,
                                             k * QN, (k + 1) * QN, msg, msgS);
        k_gconvB<false><<<QN / 4, 256, 0, stream>>>(row_ptr, dis, H8, S, msg, msgS,
                                                    b1, k * QN, A, nullptr, nullptr);
    }

    // ---- conv2 (pool fused) ----
    k_matmul_b<HH, 1><<<MMB, 256, 0, stream>>>(A, W2, dis, H8, S);
    hipMemsetAsync(g, 0, (size_t)GG * HH * sizeof(float), stream);
    for (int k = 0; k < NQ; ++k) {
        k_scatA<<<NN / 16, 256, 0, stream>>>(row_ptr2, csc_pos, H8, S, row_ptr,
                                             k * QN, (k + 1) * QN, msg, msgS);
        k_gconvB<true><<<QN / 4, 256, 0, stream>>>(row_ptr, dis, H8, S, msg, msgS,
                                                   b2, k * QN, nullptr, bat, g);
    }

    // ---- head ----
    k_head1<<<(GG * HH) / 256, 256, 0, stream>>>(g, Wl1, bl1, g2);
    k_head2<<<1, 128, 0, stream>>>(g2, Wl2, bl2, out);
}

// Round 11
// 299.922 us; speedup vs baseline: 2.0062x; 2.0062x over previous
//
#include <hip/hip_runtime.h>

#define NN 100000
#define EE 1000000
#define FF 128
#define HH 64
#define GG 128
#define NB 391   // scan blocks: 391*256 = 100096 >= NN
#define MMB 1563 // matmul-1 blocks: ceil(NN/64)

__device__ inline unsigned short f2bf(float f) {
    unsigned u = __float_as_uint(f);
    u += 0x7fffu + ((u >> 16) & 1u);
    return (unsigned short)(u >> 16);
}

// ---------- CSR build (unpadded; self handled by clamp+mask in gconv) ----------
__global__ void k_hist(const int* __restrict__ ei, int* __restrict__ cnt) {
    int e = blockIdx.x * 256 + threadIdx.x;
    if (e < EE) atomicAdd(&cnt[ei[EE + e]], 1);
}

__global__ void k_scan1(const int* __restrict__ cnt, int* __restrict__ part,
                        float* __restrict__ dis) {
    int i = blockIdx.x * 256 + threadIdx.x;
    int c = (i < NN) ? cnt[i] : 0;
    if (i < NN) dis[i] = rsqrtf((float)(c + 1));
    int v = (i < NN) ? c : 0;
    for (int o = 1; o < 64; o <<= 1) v += __shfl_xor(v, o);
    __shared__ int ws[4];
    if ((threadIdx.x & 63) == 0) ws[threadIdx.x >> 6] = v;
    __syncthreads();
    if (threadIdx.x == 0) part[blockIdx.x] = ws[0] + ws[1] + ws[2] + ws[3];
}

__global__ void k_scan2(int* __restrict__ part) {   // exclusive scan, 1 block
    __shared__ int buf[512];
    int t = threadIdx.x;
    int v = (t < NB) ? part[t] : 0;
    buf[t] = v; __syncthreads();
    for (int o = 1; o < 512; o <<= 1) {
        int u = (t >= o) ? buf[t - o] : 0;
        __syncthreads();
        buf[t] += u;
        __syncthreads();
    }
    if (t < NB) part[t] = buf[t] - v;
}

__global__ void k_scan3(const int* __restrict__ cnt, const int* __restrict__ part,
                        int* __restrict__ row_ptr, int* __restrict__ cursor) {
    int i = blockIdx.x * 256 + threadIdx.x;
    int v = (i < NN) ? cnt[i] : 0;
    int lane = threadIdx.x & 63, w = threadIdx.x >> 6;
    int incl = v;
    for (int o = 1; o < 64; o <<= 1) { int u = __shfl_up(incl, o); if (lane >= o) incl += u; }
    __shared__ int ws[4];
    if (lane == 63) ws[w] = incl;
    __syncthreads();
    int woff = 0;
    for (int k = 0; k < w; ++k) woff += ws[k];
    int excl = incl - v + woff + part[blockIdx.x];
    if (i < NN) {
        row_ptr[i] = excl;
        cursor[i]  = excl;
    }
    if (i == 0) row_ptr[NN] = EE;
}

// ---------- matmul body: int8 row output, bf16 scale hidden in the 16 byte-0 LSBs ----------
template<int K>
__device__ __forceinline__ void
mm_body(const float* __restrict__ X, const float* __restrict__ W,
        const float* __restrict__ dis, unsigned* __restrict__ Y8,
        float* __restrict__ Wl, int bid) {
    for (int i = threadIdx.x; i < K * HH; i += 256) Wl[i] = W[i];
    __syncthreads();
    const int lane = threadIdx.x & 63;
    const int wv   = threadIdx.x >> 6;
    const int c4   = (lane & 15) * 4;
    const int rsg  = lane >> 4;
    const int r0   = bid * 64 + wv * 16 + rsg * 4;

    const float* xr0; const float* xr1; const float* xr2; const float* xr3;
    {
        int a = r0, b_ = r0 + 1, c = r0 + 2, d = r0 + 3;
        if (a > NN - 1) a = NN - 1;
        if (b_ > NN - 1) b_ = NN - 1;
        if (c > NN - 1) c = NN - 1;
        if (d > NN - 1) d = NN - 1;
        xr0 = X + (size_t)a * K; xr1 = X + (size_t)b_ * K;
        xr2 = X + (size_t)c * K; xr3 = X + (size_t)d * K;
    }
    float4 acc0 = {0,0,0,0}, acc1 = {0,0,0,0}, acc2 = {0,0,0,0}, acc3 = {0,0,0,0};

#pragma unroll 8
    for (int k4 = 0; k4 < K / 4; ++k4) {
        const float4 x0 = *(const float4*)(xr0 + k4 * 4);
        const float4 x1 = *(const float4*)(xr1 + k4 * 4);
        const float4 x2 = *(const float4*)(xr2 + k4 * 4);
        const float4 x3 = *(const float4*)(xr3 + k4 * 4);
        const float4 w0 = *(const float4*)&Wl[(k4 * 4 + 0) * HH + c4];
        const float4 w1 = *(const float4*)&Wl[(k4 * 4 + 1) * HH + c4];
        const float4 w2 = *(const float4*)&Wl[(k4 * 4 + 2) * HH + c4];
        const float4 w3 = *(const float4*)&Wl[(k4 * 4 + 3) * HH + c4];
#define FMA4(A, XS) \
        A.x = fmaf(XS.x, w0.x, A.x); A.y = fmaf(XS.x, w0.y, A.y); \
        A.z = fmaf(XS.x, w0.z, A.z); A.w = fmaf(XS.x, w0.w, A.w); \
        A.x = fmaf(XS.y, w1.x, A.x); A.y = fmaf(XS.y, w1.y, A.y); \
        A.z = fmaf(XS.y, w1.z, A.z); A.w = fmaf(XS.y, w1.w, A.w); \
        A.x = fmaf(XS.z, w2.x, A.x); A.y = fmaf(XS.z, w2.y, A.y); \
        A.z = fmaf(XS.z, w2.z, A.z); A.w = fmaf(XS.z, w2.w, A.w); \
        A.x = fmaf(XS.w, w3.x, A.x); A.y = fmaf(XS.w, w3.y, A.y); \
        A.z = fmaf(XS.w, w3.z, A.z); A.w = fmaf(XS.w, w3.w, A.w);
        FMA4(acc0, x0) FMA4(acc1, x1) FMA4(acc2, x2) FMA4(acc3, x3)
#undef FMA4
    }
    // STORE: quantize row to int8 with rowmax scale; embed f2bf(m/127) bit li
    // into byte0's LSB of word li (li = c4>>2). Decode side clears that LSB.
#define STORE(I, A) { \
        const int r = r0 + I; \
        if (r < NN) { \
            const float d = dis[r]; \
            const float ax = A.x * d, ay = A.y * d, az = A.z * d, aw = A.w * d; \
            float m = fmaxf(fmaxf(fabsf(ax), fabsf(ay)), fmaxf(fabsf(az), fabsf(aw))); \
            m = fmaxf(m, __shfl_xor(m, 1)); m = fmaxf(m, __shfl_xor(m, 2)); \
            m = fmaxf(m, __shfl_xor(m, 4)); m = fmaxf(m, __shfl_xor(m, 8)); \
            const float inv = 127.0f / m; \
            int q0 = __float2int_rn(ax * inv), q1 = __float2int_rn(ay * inv); \
            int q2 = __float2int_rn(az * inv), q3 = __float2int_rn(aw * inv); \
            if (m == 0.0f) { q0 = q1 = q2 = q3 = 0; } \
            const unsigned short sb = f2bf(m * (1.0f / 127.0f)); \
            const unsigned bit = (sb >> (c4 >> 2)) & 1u; \
            const unsigned pk = ((q0 & 0xfe) | bit) | ((q1 & 0xff) << 8) | \
                                ((q2 & 0xff) << 16) | ((q3 & 0xff) << 24); \
            Y8[(size_t)r * 16 + (c4 >> 2)] = pk; \
        } }
    STORE(0, acc0) STORE(1, acc1) STORE(2, acc2) STORE(3, acc3)
#undef STORE
}

template<int K>
__global__ __launch_bounds__(256) void
k_matmul_b(const float* __restrict__ X, const float* __restrict__ W,
           const float* __restrict__ dis, unsigned* __restrict__ Y8) {
    __shared__ float Wl[K * HH];
    mm_body<K>(X, W, dis, Y8, Wl, blockIdx.x);
}

// fused: blocks [0,MMB) run matmul-1 (K=128); rest place edges into CSR
__global__ __launch_bounds__(256) void
k_mm1_place(const float* __restrict__ X, const float* __restrict__ W,
            const float* __restrict__ dis, unsigned* __restrict__ Y8,
            const int* __restrict__ ei, int* __restrict__ cursor,
            int* __restrict__ srcs) {
    __shared__ float Wl[FF * HH];
    if (blockIdx.x < MMB) {
        mm_body<FF>(X, W, dis, Y8, Wl, blockIdx.x);
    } else {
        int e = (blockIdx.x - MMB) * 256 + threadIdx.x;
        if (e < EE) {
            int d = ei[EE + e];
            int p = atomicAdd(&cursor[d], 1);
            srcs[p] = ei[e];
        }
    }
}

// ---------- gather conv: ONE random request per edge ----------
// Wave per node; 16-lane team per row, 4 rows per load instr. Scale is
// recovered from the row itself: ballot of byte0 LSBs -> 16 bits -> bf16.
template<bool POOL>
__global__ __launch_bounds__(256) void
k_gconv(const int* __restrict__ row_ptr, const int* __restrict__ srcs,
        const float* __restrict__ dis, const unsigned* __restrict__ H8,
        const float* __restrict__ b, float* __restrict__ Out,
        const int* __restrict__ batch, float* __restrict__ g) {
    const int node = blockIdx.x * 4 + (threadIdx.x >> 6);
    const int lane = threadIdx.x & 63;
    const int li   = lane & 15;       // word index within row
    const int qr   = lane >> 4;       // row slot 0..3 per load
    const int p0   = row_ptr[node];
    const int deg  = row_ptr[node + 1] - p0;
    const int items  = deg + 1;              // + self
    const int nbatch = (items + 7) >> 3;     // 8 items / batch

    float ac0 = 0.f, ac1 = 0.f, ac2 = 0.f, ac3 = 0.f;

#define IDX(bi, dA, dB) { \
        const int iA = 8 * (bi) + qr, iB = iA + 4; \
        dA = srcs[p0 + (iA < deg ? iA : 0)]; \
        dB = srcs[p0 + (iB < deg ? iB : 0)]; }
#define VAL(bi, sA, sB, vA, vB) { \
        const int iA = 8 * (bi) + qr, iB = iA + 4; \
        const int rA = (iA < deg) ? sA : node; \
        const int rB = (iB < deg) ? sB : node; \
        vA = H8[(size_t)rA * 16 + li]; \
        vB = H8[(size_t)rB * 16 + li]; }
#define CONSUME(bi, vA, vB) { \
        const int iA = 8 * (bi) + qr, iB = iA + 4; \
        const unsigned long long MA = __ballot((vA & 1u) != 0u); \
        const unsigned long long MB = __ballot((vB & 1u) != 0u); \
        float s0 = __uint_as_float(((unsigned)((MA >> (qr * 16)) & 0xffffull)) << 16); \
        float s1 = __uint_as_float(((unsigned)((MB >> (qr * 16)) & 0xffffull)) << 16); \
        s0 = (iA <= deg) ? s0 : 0.f; \
        s1 = (iB <= deg) ? s1 : 0.f; \
        ac0 = fmaf(s0, (float)(signed char)(vA & 0xfeu), ac0); \
        ac1 = fmaf(s0, (float)(signed char)(vA >> 8 ), ac1); \
        ac2 = fmaf(s0, (float)(signed char)(vA >> 16), ac2); \
        ac3 = fmaf(s0, (float)(signed char)(vA >> 24), ac3); \
        ac0 = fmaf(s1, (float)(signed char)(vB & 0xfeu), ac0); \
        ac1 = fmaf(s1, (float)(signed char)(vB >> 8 ), ac1); \
        ac2 = fmaf(s1, (float)(signed char)(vB >> 16), ac2); \
        ac3 = fmaf(s1, (float)(signed char)(vB >> 24), ac3); }

    int sA0, sA1, sB0, sB1;
    unsigned vA0, vA1;
    IDX(0, sA0, sA1);
    VAL(0, sA0, sA1, vA0, vA1);
    IDX(1, sB0, sB1);
    for (int bi = 1; bi < nbatch; ++bi) {
        unsigned vB0, vB1;
        VAL(bi, sB0, sB1, vB0, vB1);
        IDX(bi + 1, sB0, sB1);               // clamped beyond end; cheap hits
        CONSUME(bi - 1, vA0, vA1);
        vA0 = vB0; vA1 = vB1;
    }
    CONSUME(nbatch - 1, vA0, vA1);
#undef IDX
#undef VAL
#undef CONSUME

    // reduce across the 4 row slots
    ac0 += __shfl_xor(ac0, 16); ac0 += __shfl_xor(ac0, 32);
    ac1 += __shfl_xor(ac1, 16); ac1 += __shfl_xor(ac1, 32);
    ac2 += __shfl_xor(ac2, 16); ac2 += __shfl_xor(ac2, 32);
    ac3 += __shfl_xor(ac3, 16); ac3 += __shfl_xor(ac3, 32);
    // redistribute so lane holds col = lane (full-wave 4B store)
    const float c0 = __shfl(ac0, lane >> 2);
    const float c1 = __shfl(ac1, lane >> 2);
    const float c2 = __shfl(ac2, lane >> 2);
    const float c3 = __shfl(ac3, lane >> 2);
    const int m = lane & 3;
    float acc = (m == 0) ? c0 : (m == 1) ? c1 : (m == 2) ? c2 : c3;

    const float dd = dis[node];
    float v = acc * dd + b[lane];
    v = fmaxf(v, 0.0f);
    if (POOL) {
        unsafeAtomicAdd(&g[(size_t)batch[node] * HH + lane], v);
    } else {
        Out[(size_t)node * HH + lane] = v;
    }
}

// ---------- head ----------
__global__ void k_head1(const float* __restrict__ g, const float* __restrict__ W,
                        const float* __restrict__ b, float* __restrict__ g2) {
    const int idx = blockIdx.x * 256 + threadIdx.x;
    const int row = idx >> 6;
    const int col = idx & 63;
    const float* gr = g + (size_t)row * HH;
    float acc = b[col];
#pragma unroll
    for (int k = 0; k < HH; ++k) acc = fmaf(gr[k], W[k * HH + col], acc);
    g2[idx] = acc > 0.0f ? acc : 0.0f;
}

__global__ void k_head2(const float* __restrict__ g2, const float* __restrict__ W,
                        const float* __restrict__ b, float* __restrict__ out) {
    const int r = threadIdx.x;
    if (r >= GG) return;
    const float* gr = g2 + (size_t)r * HH;
    float acc = 0.0f;
#pragma unroll
    for (int k = 0; k < HH; ++k) acc = fmaf(gr[k], W[k], acc);
    out[r] = acc + b[0];
}

extern "C" void kernel_launch(void* const* d_in, const int* in_sizes, int n_in,
                              void* d_out, int out_size, void* d_ws, size_t ws_size,
                              hipStream_t stream) {
    const float* x   = (const float*)d_in[0];
    const int*   ei  = (const int*)d_in[1];
    const int*   bat = (const int*)d_in[2];
    const float* W1  = (const float*)d_in[3];
    const float* b1  = (const float*)d_in[4];
    const float* W2  = (const float*)d_in[5];
    const float* b2  = (const float*)d_in[6];
    const float* Wl1 = (const float*)d_in[7];
    const float* bl1 = (const float*)d_in[8];
    const float* Wl2 = (const float*)d_in[9];
    const float* bl2 = (const float*)d_in[10];
    float* out = (float*)d_out;

    char* w = (char*)d_ws;
    float*    dis     = (float*)(w);                  // 400,128 B
    int*      cnt     = (int*)  (w + 400128);         // 400,128 B
    int*      row_ptr = (int*)  (w + 800256);         // 400,384 B
    int*      cursor  = (int*)  (w + 1200640);        // 400,128 B
    int*      part    = (int*)  (w + 1600768);        // 2,048 B
    int*      srcs    = (int*)  (w + 1602816);        // 4,000,000 B (E ints)
    unsigned* H8      = (unsigned*)(w + 5602816);     // N*16 uints = 6,400,000 B
    float*    A       = (float*)(w + 12002816);       // 25,600,000 B
    float*    g       = (float*)(w + 37602816);       // pool + head scratch
    float*    g2      = g + GG * HH;

    // ---- CSR build ----
    hipMemsetAsync(cnt, 0, (size_t)NN * sizeof(int), stream);
    k_hist <<<(EE + 255) / 256, 256, 0, stream>>>(ei, cnt);
    k_scan1<<<NB, 256, 0, stream>>>(cnt, part, dis);
    k_scan2<<<1, 512, 0, stream>>>(part);
    k_scan3<<<NB, 256, 0, stream>>>(cnt, part, row_ptr, cursor);

    // ---- conv1 matmul fused with CSR edge placement (independent work) ----
    k_mm1_place<<<MMB + (EE + 255) / 256, 256, 0, stream>>>(x, W1, dis, H8, ei, cursor, srcs);
    k_gconv<false><<<NN / 4, 256, 0, stream>>>(row_ptr, srcs, dis, H8, b1, A, nullptr, nullptr);

    // ---- conv2 (pool fused) ----
    k_matmul_b<HH><<<(NN + 63) / 64, 256, 0, stream>>>(A, W2, dis, H8);
    hipMemsetAsync(g, 0, (size_t)GG * HH * sizeof(float), stream);
    k_gconv<true><<<NN / 4, 256, 0, stream>>>(row_ptr, srcs, dis, H8, b2, nullptr, bat, g);

    // ---- head ----
    k_head1<<<(GG * HH) / 256, 256, 0, stream>>>(g, Wl1, bl1, g2);
    k_head2<<<1, 128, 0, stream>>>(g2, Wl2, bl2, out);
}

// Round 12
// 280.041 us; speedup vs baseline: 2.1486x; 1.0710x over previous
//
#include <hip/hip_runtime.h>

#define NN 100000
#define EE 1000000
#define FF 128
#define HH 64
#define GG 128
#define NB 391   // scan blocks: 391*256 = 100096 >= NN
#define MMB 1563 // matmul-1 blocks: ceil(NN/64)
#define GCB 2048 // persistent gconv blocks (8/CU)

__device__ inline unsigned short f2bf(float f) {
    unsigned u = __float_as_uint(f);
    u += 0x7fffu + ((u >> 16) & 1u);
    return (unsigned short)(u >> 16);
}
__device__ inline float bf2f(unsigned short h) {
    return __uint_as_float((unsigned)h << 16);
}

// ---------- CSR build ----------
__global__ void k_hist(const int* __restrict__ ei, int* __restrict__ cnt) {
    int e = blockIdx.x * 256 + threadIdx.x;
    if (e < EE) atomicAdd(&cnt[ei[EE + e]], 1);
}

__global__ void k_scan1(const int* __restrict__ cnt, int* __restrict__ part,
                        float* __restrict__ dis) {
    int i = blockIdx.x * 256 + threadIdx.x;
    int c = (i < NN) ? cnt[i] : 0;
    if (i < NN) dis[i] = rsqrtf((float)(c + 1));
    int v = (i < NN) ? c : 0;
    for (int o = 1; o < 64; o <<= 1) v += __shfl_xor(v, o);
    __shared__ int ws[4];
    if ((threadIdx.x & 63) == 0) ws[threadIdx.x >> 6] = v;
    __syncthreads();
    if (threadIdx.x == 0) part[blockIdx.x] = ws[0] + ws[1] + ws[2] + ws[3];
}

__global__ void k_scan2(int* __restrict__ part) {   // exclusive scan, 1 block
    __shared__ int buf[512];
    int t = threadIdx.x;
    int v = (t < NB) ? part[t] : 0;
    buf[t] = v; __syncthreads();
    for (int o = 1; o < 512; o <<= 1) {
        int u = (t >= o) ? buf[t - o] : 0;
        __syncthreads();
        buf[t] += u;
        __syncthreads();
    }
    if (t < NB) part[t] = buf[t] - v;
}

__global__ void k_scan3(const int* __restrict__ cnt, const int* __restrict__ part,
                        int* __restrict__ row_ptr, int* __restrict__ cursor) {
    int i = blockIdx.x * 256 + threadIdx.x;
    int v = (i < NN) ? cnt[i] : 0;
    int lane = threadIdx.x & 63, w = threadIdx.x >> 6;
    int incl = v;
    for (int o = 1; o < 64; o <<= 1) { int u = __shfl_up(incl, o); if (lane >= o) incl += u; }
    __shared__ int ws[4];
    if (lane == 63) ws[w] = incl;
    __syncthreads();
    int woff = 0;
    for (int k = 0; k < w; ++k) woff += ws[k];
    int excl = incl - v + woff + part[blockIdx.x];
    if (i < NN) {
        row_ptr[i] = excl;
        cursor[i]  = excl;
    }
    if (i == 0) row_ptr[NN] = EE;
}

// ---------- matmul body: int8 row-quantized output (scale S[r]) ----------
template<int K, int XBF>
__device__ __forceinline__ void
mm_body(const void* __restrict__ Xv, const float* __restrict__ W,
        const float* __restrict__ dis, unsigned* __restrict__ Y8,
        float* __restrict__ S, float* __restrict__ Wl, int bid) {
    for (int i = threadIdx.x; i < K * HH; i += 256) Wl[i] = W[i];
    __syncthreads();
    const int lane = threadIdx.x & 63;
    const int wv   = threadIdx.x >> 6;
    const int c4   = (lane & 15) * 4;
    const int rsg  = lane >> 4;
    const int r0   = bid * 64 + wv * 16 + rsg * 4;

    const char* Xb = (const char*)Xv;
    const size_t rb = (size_t)K * (XBF ? 2 : 4);
    const char* xr0; const char* xr1; const char* xr2; const char* xr3;
    {
        int a = r0, b_ = r0 + 1, c = r0 + 2, d = r0 + 3;
        if (a > NN - 1) a = NN - 1;
        if (b_ > NN - 1) b_ = NN - 1;
        if (c > NN - 1) c = NN - 1;
        if (d > NN - 1) d = NN - 1;
        xr0 = Xb + (size_t)a * rb; xr1 = Xb + (size_t)b_ * rb;
        xr2 = Xb + (size_t)c * rb; xr3 = Xb + (size_t)d * rb;
    }
    float4 acc0 = {0,0,0,0}, acc1 = {0,0,0,0}, acc2 = {0,0,0,0}, acc3 = {0,0,0,0};

#pragma unroll 8
    for (int k4 = 0; k4 < K / 4; ++k4) {
        float4 x0, x1, x2, x3;
        if (XBF) {
            ushort4 u0 = *(const ushort4*)(xr0 + k4 * 8);
            ushort4 u1 = *(const ushort4*)(xr1 + k4 * 8);
            ushort4 u2 = *(const ushort4*)(xr2 + k4 * 8);
            ushort4 u3 = *(const ushort4*)(xr3 + k4 * 8);
            x0 = {bf2f(u0.x), bf2f(u0.y), bf2f(u0.z), bf2f(u0.w)};
            x1 = {bf2f(u1.x), bf2f(u1.y), bf2f(u1.z), bf2f(u1.w)};
            x2 = {bf2f(u2.x), bf2f(u2.y), bf2f(u2.z), bf2f(u2.w)};
            x3 = {bf2f(u3.x), bf2f(u3.y), bf2f(u3.z), bf2f(u3.w)};
        } else {
            x0 = *(const float4*)(xr0 + k4 * 16);
            x1 = *(const float4*)(xr1 + k4 * 16);
            x2 = *(const float4*)(xr2 + k4 * 16);
            x3 = *(const float4*)(xr3 + k4 * 16);
        }
        const float4 w0 = *(const float4*)&Wl[(k4 * 4 + 0) * HH + c4];
        const float4 w1 = *(const float4*)&Wl[(k4 * 4 + 1) * HH + c4];
        const float4 w2 = *(const float4*)&Wl[(k4 * 4 + 2) * HH + c4];
        const float4 w3 = *(const float4*)&Wl[(k4 * 4 + 3) * HH + c4];
#define FMA4(A, XS) \
        A.x = fmaf(XS.x, w0.x, A.x); A.y = fmaf(XS.x, w0.y, A.y); \
        A.z = fmaf(XS.x, w0.z, A.z); A.w = fmaf(XS.x, w0.w, A.w); \
        A.x = fmaf(XS.y, w1.x, A.x); A.y = fmaf(XS.y, w1.y, A.y); \
        A.z = fmaf(XS.y, w1.z, A.z); A.w = fmaf(XS.y, w1.w, A.w); \
        A.x = fmaf(XS.z, w2.x, A.x); A.y = fmaf(XS.z, w2.y, A.y); \
        A.z = fmaf(XS.z, w2.z, A.z); A.w = fmaf(XS.z, w2.w, A.w); \
        A.x = fmaf(XS.w, w3.x, A.x); A.y = fmaf(XS.w, w3.y, A.y); \
        A.z = fmaf(XS.w, w3.z, A.z); A.w = fmaf(XS.w, w3.w, A.w);
        FMA4(acc0, x0) FMA4(acc1, x1) FMA4(acc2, x2) FMA4(acc3, x3)
#undef FMA4
    }
#define STORE(I, A) { \
        const int r = r0 + I; \
        if (r < NN) { \
            const float d = dis[r]; \
            const float ax = A.x * d, ay = A.y * d, az = A.z * d, aw = A.w * d; \
            float m = fmaxf(fmaxf(fabsf(ax), fabsf(ay)), fmaxf(fabsf(az), fabsf(aw))); \
            m = fmaxf(m, __shfl_xor(m, 1)); m = fmaxf(m, __shfl_xor(m, 2)); \
            m = fmaxf(m, __shfl_xor(m, 4)); m = fmaxf(m, __shfl_xor(m, 8)); \
            const float inv = 127.0f / m; \
            int q0 = __float2int_rn(ax * inv), q1 = __float2int_rn(ay * inv); \
            int q2 = __float2int_rn(az * inv), q3 = __float2int_rn(aw * inv); \
            if (m == 0.0f) { q0 = q1 = q2 = q3 = 0; } \
            const unsigned pk = (q0 & 0xff) | ((q1 & 0xff) << 8) | \
                                ((q2 & 0xff) << 16) | ((q3 & 0xff) << 24); \
            Y8[(size_t)r * 16 + (c4 >> 2)] = pk; \
            if (c4 == 0) S[r] = m * (1.0f / 127.0f); \
        } }
    STORE(0, acc0) STORE(1, acc1) STORE(2, acc2) STORE(3, acc3)
#undef STORE
}

template<int K, int XBF>
__global__ __launch_bounds__(256) void
k_matmul_b(const void* __restrict__ X, const float* __restrict__ W,
           const float* __restrict__ dis, unsigned* __restrict__ Y8,
           float* __restrict__ S) {
    __shared__ float Wl[K * HH];
    mm_body<K, XBF>(X, W, dis, Y8, S, Wl, blockIdx.x);
}

// fused: blocks [0,MMB) run matmul-1 (K=128); rest place edges into CSR
__global__ __launch_bounds__(256) void
k_mm1_place(const float* __restrict__ X, const float* __restrict__ W,
            const float* __restrict__ dis, unsigned* __restrict__ Y8,
            float* __restrict__ S, const int* __restrict__ ei,
            int* __restrict__ cursor, int* __restrict__ srcs) {
    __shared__ float Wl[FF * HH];
    if (blockIdx.x < MMB) {
        mm_body<FF, 0>(X, W, dis, Y8, S, Wl, blockIdx.x);
    } else {
        int e = (blockIdx.x - MMB) * 256 + threadIdx.x;
        if (e < EE) {
            int d = ei[EE + e];
            int p = atomicAdd(&cursor[d], 1);
            srcs[p] = ei[e];
        }
    }
}

// ---------- gather conv: persistent waves, grid-stride over nodes ----------
// 2048 blocks x 4 waves = 8192 resident waves (full occupancy), each walking
// ~12 nodes. R9 numerics: int8 row (1 line) + S scale. Nontemporal for the
// streaming srcs reads and bf16 A stores (protect H8's L2 residency).
template<bool POOL>
__global__ __launch_bounds__(256) void
k_gconv(const int* __restrict__ row_ptr, const int* __restrict__ srcs,
        const float* __restrict__ dis, const unsigned* __restrict__ H8,
        const float* __restrict__ S, const float* __restrict__ b,
        unsigned short* __restrict__ Out, const int* __restrict__ batch,
        float* __restrict__ g) {
    const int lane = threadIdx.x & 63;
    const int li   = lane & 15;       // word index within row
    const int qr   = lane >> 4;       // row slot 0..3 per load
    const float bl = b[lane];         // hoisted: constant across nodes

    for (int node = blockIdx.x * 4 + (threadIdx.x >> 6); node < NN; node += GCB * 4) {
        const int p0   = row_ptr[node];
        const int deg  = row_ptr[node + 1] - p0;
        const int nbatch = (deg + 8) >> 3;     // items = deg+1 (self)

        float ac0 = 0.f, ac1 = 0.f, ac2 = 0.f, ac3 = 0.f;

#define IDX(bi, dA, dB) { \
        const int iA = 8 * (bi) + qr, iB = iA + 4; \
        dA = __builtin_nontemporal_load(srcs + p0 + (iA < deg ? iA : 0)); \
        dB = __builtin_nontemporal_load(srcs + p0 + (iB < deg ? iB : 0)); }
#define VAL(bi, sA, sB, vA, vB, gA, gB) { \
        const int iA = 8 * (bi) + qr, iB = iA + 4; \
        const int rA = (iA < deg) ? sA : node; \
        const int rB = (iB < deg) ? sB : node; \
        vA = H8[(size_t)rA * 16 + li];  gA = S[rA]; \
        vB = H8[(size_t)rB * 16 + li];  gB = S[rB]; }
#define CONSUME(bi, vA, vB, gA, gB) { \
        const int iA = 8 * (bi) + qr, iB = iA + 4; \
        const float s0 = (iA <= deg) ? gA : 0.f; \
        const float s1 = (iB <= deg) ? gB : 0.f; \
        ac0 = fmaf(s0, (float)(signed char)(vA      ), ac0); \
        ac1 = fmaf(s0, (float)(signed char)(vA >> 8 ), ac1); \
        ac2 = fmaf(s0, (float)(signed char)(vA >> 16), ac2); \
        ac3 = fmaf(s0, (float)(signed char)(vA >> 24), ac3); \
        ac0 = fmaf(s1, (float)(signed char)(vB      ), ac0); \
        ac1 = fmaf(s1, (float)(signed char)(vB >> 8 ), ac1); \
        ac2 = fmaf(s1, (float)(signed char)(vB >> 16), ac2); \
        ac3 = fmaf(s1, (float)(signed char)(vB >> 24), ac3); }

        int sA0, sA1, sB0, sB1;
        unsigned vA0, vA1;
        float gA0, gA1;
        IDX(0, sA0, sA1);
        VAL(0, sA0, sA1, vA0, vA1, gA0, gA1);
        IDX(1, sB0, sB1);
        for (int bi = 1; bi < nbatch; ++bi) {
            unsigned vB0, vB1;
            float gB0, gB1;
            VAL(bi, sB0, sB1, vB0, vB1, gB0, gB1);
            IDX(bi + 1, sB0, sB1);               // clamped beyond end
            CONSUME(bi - 1, vA0, vA1, gA0, gA1);
            vA0 = vB0; vA1 = vB1; gA0 = gB0; gA1 = gB1;
        }
        CONSUME(nbatch - 1, vA0, vA1, gA0, gA1);
#undef IDX
#undef VAL
#undef CONSUME

        // reduce across the 4 row slots
        ac0 += __shfl_xor(ac0, 16); ac0 += __shfl_xor(ac0, 32);
        ac1 += __shfl_xor(ac1, 16); ac1 += __shfl_xor(ac1, 32);
        ac2 += __shfl_xor(ac2, 16); ac2 += __shfl_xor(ac2, 32);
        ac3 += __shfl_xor(ac3, 16); ac3 += __shfl_xor(ac3, 32);
        // redistribute so lane holds col = lane
        const float c0 = __shfl(ac0, lane >> 2);
        const float c1 = __shfl(ac1, lane >> 2);
        const float c2 = __shfl(ac2, lane >> 2);
        const float c3 = __shfl(ac3, lane >> 2);
        const int m = lane & 3;
        const float acc = (m == 0) ? c0 : (m == 1) ? c1 : (m == 2) ? c2 : c3;

        float v = acc * dis[node] + bl;
        v = fmaxf(v, 0.0f);
        if (POOL) {
            unsafeAtomicAdd(&g[(size_t)batch[node] * HH + lane], v);
        } else {
            __builtin_nontemporal_store(f2bf(v), Out + (size_t)node * HH + lane);
        }
    }
}

// ---------- head ----------
__global__ void k_head1(const float* __restrict__ g, const float* __restrict__ W,
                        const float* __restrict__ b, float* __restrict__ g2) {
    const int idx = blockIdx.x * 256 + threadIdx.x;
    const int row = idx >> 6;
    const int col = idx & 63;
    const float* gr = g + (size_t)row * HH;
    float acc = b[col];
#pragma unroll
    for (int k = 0; k < HH; ++k) acc = fmaf(gr[k], W[k * HH + col], acc);
    g2[idx] = acc > 0.0f ? acc : 0.0f;
}

__global__ void k_head2(const float* __restrict__ g2, const float* __restrict__ W,
                        const float* __restrict__ b, float* __restrict__ out) {
    const int r = threadIdx.x;
    if (r >= GG) return;
    const float* gr = g2 + (size_t)r * HH;
    float acc = 0.0f;
#pragma unroll
    for (int k = 0; k < HH; ++k) acc = fmaf(gr[k], W[k], acc);
    out[r] = acc + b[0];
}

extern "C" void kernel_launch(void* const* d_in, const int* in_sizes, int n_in,
                              void* d_out, int out_size, void* d_ws, size_t ws_size,
                              hipStream_t stream) {
    const float* x   = (const float*)d_in[0];
    const int*   ei  = (const int*)d_in[1];
    const int*   bat = (const int*)d_in[2];
    const float* W1  = (const float*)d_in[3];
    const float* b1  = (const float*)d_in[4];
    const float* W2  = (const float*)d_in[5];
    const float* b2  = (const float*)d_in[6];
    const float* Wl1 = (const float*)d_in[7];
    const float* bl1 = (const float*)d_in[8];
    const float* Wl2 = (const float*)d_in[9];
    const float* bl2 = (const float*)d_in[10];
    float* out = (float*)d_out;

    char* w = (char*)d_ws;
    float*    dis     = (float*)(w);                  // 400,128 B
    int*      cnt     = (int*)  (w + 400128);         // 400,128 B
    int*      row_ptr = (int*)  (w + 800256);         // 400,384 B
    int*      cursor  = (int*)  (w + 1200640);        // 400,128 B
    int*      part    = (int*)  (w + 1600768);        // 2,048 B
    int*      srcs    = (int*)  (w + 1602816);        // 4,000,000 B
    float*    S       = (float*)(w + 5602816);        // 400,128 B
    unsigned* H8      = (unsigned*)(w + 6002944);     // 6,400,000 B
    unsigned short* A = (unsigned short*)(w + 12402944); // bf16, 12,800,000 B
    float*    g       = (float*)(w + 25202944);       // pool + head scratch
    float*    g2      = g + GG * HH;

    // ---- CSR build ----
    hipMemsetAsync(cnt, 0, (size_t)NN * sizeof(int), stream);
    k_hist <<<(EE + 255) / 256, 256, 0, stream>>>(ei, cnt);
    k_scan1<<<NB, 256, 0, stream>>>(cnt, part, dis);
    k_scan2<<<1, 512, 0, stream>>>(part);
    k_scan3<<<NB, 256, 0, stream>>>(cnt, part, row_ptr, cursor);

    // ---- conv1 matmul fused with CSR edge placement ----
    k_mm1_place<<<MMB + (EE + 255) / 256, 256, 0, stream>>>(x, W1, dis, H8, S, ei, cursor, srcs);
    k_gconv<false><<<GCB, 256, 0, stream>>>(row_ptr, srcs, dis, H8, S, b1, A, nullptr, nullptr);

    // ---- conv2 (pool fused) ----
    k_matmul_b<HH, 1><<<MMB, 256, 0, stream>>>(A, W2, dis, H8, S);
    hipMemsetAsync(g, 0, (size_t)GG * HH * sizeof(float), stream);
    k_gconv<true><<<GCB, 256, 0, stream>>>(row_ptr, srcs, dis, H8, S, b2, nullptr, bat, g);

    // ---- head ----
    k_head1<<<(GG * HH) / 256, 256, 0, stream>>>(g, Wl1, bl1, g2);
    k_head2<<<1, 128, 0, stream>>>(g2, Wl2, bl2, out);
}